// Round 11
// baseline (289.467 us; speedup 1.0000x reference)
//
#include <hip/hip_runtime.h>

typedef _Float16 f16;
typedef float f32x4 __attribute__((ext_vector_type(4)));
typedef _Float16 f16x8 __attribute__((ext_vector_type(8)));
typedef _Float16 f16x4 __attribute__((ext_vector_type(4)));
typedef _Float16 f16x2 __attribute__((ext_vector_type(2)));

#define MFMA16(a, b, c) __builtin_amdgcn_mfma_f32_16x16x32_f16((a), (b), (c), 0, 0, 0)

__device__ __forceinline__ void gld16(const void* g, void* l) {
    __builtin_amdgcn_global_load_lds((const __attribute__((address_space(1))) unsigned int*)g,
                                     (__attribute__((address_space(3))) unsigned int*)l, 16, 0, 0);
}

// ---------------- merged fp32 -> fp16 cast for all 5 tensors ----------------
__global__ __launch_bounds__(256) void cvt_all(const float* __restrict__ hs, const float* __restrict__ qw,
                                               const float* __restrict__ kw, const float* __restrict__ vw,
                                               const float* __restrict__ ow, f16* __restrict__ hsb,
                                               f16* __restrict__ wqkv, f16* __restrict__ owb) {
    long g = (long)(blockIdx.x * 256 + threadIdx.x) * 8;
    const float* src;
    f16* dst;
    long off;
    if (g < 10485760L) { src = hs; dst = hsb; off = g; }
    else if (g < 15728640L) { src = qw; dst = wqkv; off = g - 10485760L; }
    else if (g < 18350080L) { src = kw; dst = wqkv + 5242880; off = g - 15728640L; }
    else if (g < 20971520L) { src = vw; dst = wqkv + 7864320; off = g - 18350080L; }
    else { src = ow; dst = owb; off = g - 20971520L; }
    float4 a = *(const float4*)(src + off);
    float4 b = *(const float4*)(src + off + 4);
    f16x8 o;
    o[0] = (f16)a.x; o[1] = (f16)a.y; o[2] = (f16)a.z; o[3] = (f16)a.w;
    o[4] = (f16)b.x; o[5] = (f16)b.y; o[6] = (f16)b.z; o[7] = (f16)b.w;
    *(f16x8*)(dst + off) = o;
}

// ===== 256x256-tile GEMM, BK=64, 2-buf, COUNTED vmcnt(8) pipeline (T1-T5) ===
// stage(t+1) issued before compute(t); wait vmcnt(8) = stage(t) landed only —
// stage(t+1) stays in flight across the compute phase (T4, m218 lever).
template <int K, int N, int GN, bool F16OUT>
__global__ __launch_bounds__(512, 1) void gemm256(const f16* __restrict__ A, const f16* __restrict__ W,
                                                  void* __restrict__ Cv) {
    constexpr int NT = K / 64;
    __shared__ __align__(16) char lds[131072];
    const int tid = threadIdx.x;
    const int lane = tid & 63, wid = tid >> 6;
    const int wr = wid >> 2, wc = wid & 3;
    const int g = lane >> 4;
    int bid = blockIdx.x;
    int swz = (bid & 7) * ((16 * GN) >> 3) + (bid >> 3);
    const int m0 = (swz / GN) * 256, n0 = (swz % GN) * 256;

    const int kel = 8 * ((tid & 7) ^ ((tid >> 3) & 7));   // pre-swizzled k (elems)
    const int rowb = tid >> 3;                            // 0..63
    const f16* pA = A + (size_t)(m0 + rowb) * K + kel;
    const f16* pB = W + (size_t)(n0 + rowb) * K + kel;
    const int dst_o = tid * 16;

#define QSTAGE(bi, t)                                                     \
    {                                                                     \
        char* lb_ = lds + (bi) * 65536;                                   \
        int k0_ = (t) * 64;                                               \
        gld16(pA + k0_,                 lb_ + dst_o);                     \
        gld16(pA + (size_t)64 * K + k0_,  lb_ + 8192 + dst_o);            \
        gld16(pA + (size_t)128 * K + k0_, lb_ + 16384 + dst_o);           \
        gld16(pA + (size_t)192 * K + k0_, lb_ + 24576 + dst_o);           \
        gld16(pB + k0_,                 lb_ + 32768 + dst_o);             \
        gld16(pB + (size_t)64 * K + k0_,  lb_ + 40960 + dst_o);           \
        gld16(pB + (size_t)128 * K + k0_, lb_ + 49152 + dst_o);           \
        gld16(pB + (size_t)192 * K + k0_, lb_ + 57344 + dst_o);           \
    }

    const int xorv = (lane & 7) << 4;
    const int arow = wr * 128 + (lane & 15);
    const int brow = wc * 64 + (lane & 15);

    f32x4 acc[8][4] = {};

#define QCOMPUTE(bi)                                                      \
    {                                                                     \
        const char* ab_ = lds + (bi) * 65536;                             \
        const char* bb_ = ab_ + 32768;                                    \
        _Pragma("unroll")                                                 \
        for (int ks = 0; ks < 2; ++ks) {                                  \
            const int cc = (ks * 64 + g * 16) ^ xorv;                     \
            f16x8 Af[8], Bf[4];                                           \
            _Pragma("unroll")                                             \
            for (int m = 0; m < 8; ++m)                                   \
                Af[m] = *(const f16x8*)(ab_ + (arow + m * 16) * 128 + cc);\
            _Pragma("unroll")                                             \
            for (int n = 0; n < 4; ++n)                                   \
                Bf[n] = *(const f16x8*)(bb_ + (brow + n * 16) * 128 + cc);\
            __builtin_amdgcn_s_setprio(1);                                \
            _Pragma("unroll")                                             \
            for (int m = 0; m < 8; ++m)                                   \
                _Pragma("unroll")                                         \
                for (int n = 0; n < 4; ++n)                               \
                    acc[m][n] = MFMA16(Af[m], Bf[n], acc[m][n]);          \
            __builtin_amdgcn_s_setprio(0);                                \
        }                                                                 \
    }

    QSTAGE(0, 0)

#pragma unroll 1
    for (int t = 0; t < NT; ++t) {
        if (t + 1 < NT) {
            QSTAGE((t + 1) & 1, t + 1)                     // issue-early
            asm volatile("s_waitcnt vmcnt(8)" ::: "memory");  // stage(t) landed
        } else {
            asm volatile("s_waitcnt vmcnt(0)" ::: "memory");
        }
        __builtin_amdgcn_s_barrier();                      // landed for ALL waves
        __builtin_amdgcn_sched_barrier(0);
        QCOMPUTE(t & 1)
        asm volatile("s_waitcnt lgkmcnt(0)" ::: "memory");
        __builtin_amdgcn_s_barrier();                      // readers done -> buf reusable
    }

#pragma unroll
    for (int m = 0; m < 8; ++m) {
        int row = m0 + wr * 128 + m * 16 + ((lane >> 4) << 2);
#pragma unroll
        for (int n = 0; n < 4; ++n) {
            int col = n0 + wc * 64 + n * 16 + (lane & 15);
#pragma unroll
            for (int r = 0; r < 4; ++r) {
                if constexpr (F16OUT)
                    ((f16*)Cv)[(size_t)(row + r) * N + col] = (f16)acc[m][n][r];
                else
                    __builtin_nontemporal_store(acc[m][n][r],
                        &((float*)Cv)[(size_t)(row + r) * N + col]);
            }
        }
    }
#undef QSTAGE
#undef QCOMPUTE
}

// ------- merged RMSNorm+RoPE (blocks 0..12287) + V transpose (12288..12543) -
__global__ __launch_bounds__(256) void rmsvt_k(const f16* __restrict__ qkvh,
                                               const float* __restrict__ cosb, const float* __restrict__ sinb,
                                               const float* __restrict__ qnw, const float* __restrict__ knw,
                                               f16* __restrict__ qr, f16* __restrict__ kr,
                                               f16* __restrict__ vt) {
    if (blockIdx.x < 12288) {
        // ---- RMSNorm + RoPE: one wave per (b,s,head) ----
        int wid = threadIdx.x >> 6, lane = threadIdx.x & 63;
        int task = blockIdx.x * 4 + wid;
        int slot = task % 12;
        int bs = task / 12;
        int b = bs >> 11, s = bs & 2047;
        const f16* src;
        const float* w;
        f16* dst;
        if (slot < 8) {
            src = qkvh + (size_t)bs * 4096 + slot * 256;
            w = qnw;
            dst = qr + ((size_t)(b * 8 + slot) * 2048 + s) * 256;
        } else {
            int h = slot - 8;
            src = qkvh + (size_t)bs * 4096 + 2048 + h * 256;
            w = knw;
            dst = kr + ((size_t)(b * 4 + h) * 2048 + s) * 256;
        }
        int i = lane * 4;
        f16x4 xr = *(const f16x4*)(src + i);
        float4 x;
        x.x = (float)xr[0]; x.y = (float)xr[1]; x.z = (float)xr[2]; x.w = (float)xr[3];
        float ss = x.x * x.x + x.y * x.y + x.z * x.z + x.w * x.w;
#pragma unroll
        for (int o = 32; o; o >>= 1) ss += __shfl_xor(ss, o, 64);
        float rs = rsqrtf(ss * (1.0f / 256.0f) + 1e-6f);
        float4 y;
        y.x = __shfl_xor(x.x, 32, 64);
        y.y = __shfl_xor(x.y, 32, 64);
        y.z = __shfl_xor(x.z, 32, 64);
        y.w = __shfl_xor(x.w, 32, 64);
        float4 wv = *(const float4*)(w + i);
        float4 wp = *(const float4*)(w + (i ^ 128));
        float4 c = *(const float4*)(cosb + (size_t)bs * 256 + i);
        float4 sn = *(const float4*)(sinb + (size_t)bs * 256 + i);
        float sgn = (lane < 32) ? -1.0f : 1.0f;
        float n0 = x.x * rs * (1.f + wv.x), n1 = x.y * rs * (1.f + wv.y);
        float n2 = x.z * rs * (1.f + wv.z), n3 = x.w * rs * (1.f + wv.w);
        float r0 = y.x * rs * (1.f + wp.x) * sgn, r1 = y.y * rs * (1.f + wp.y) * sgn;
        float r2 = y.z * rs * (1.f + wp.z) * sgn, r3 = y.w * rs * (1.f + wp.w) * sgn;
        f16x4 outv;
        outv[0] = (f16)(n0 * c.x + r0 * sn.x);
        outv[1] = (f16)(n1 * c.y + r1 * sn.y);
        outv[2] = (f16)(n2 * c.z + r2 * sn.z);
        outv[3] = (f16)(n3 * c.w + r3 * sn.w);
        *(f16x4*)(dst + i) = outv;
    } else {
        // ---- V transpose tile ----
        __shared__ __align__(16) char Ls[64 * 516];
        int tile = blockIdx.x - 12288;   // 0..255
        int st = tile & 31;
        int by = tile >> 5;
        int b = by >> 2, kvh = by & 3;
        int tid = threadIdx.x;
        int s0 = st * 64;
        const f16* src = qkvh + ((size_t)(b * 2048 + s0)) * 4096 + 3072 + kvh * 256;
#pragma unroll
        for (int it = 0; it < 8; ++it) {
            int idx = it * 256 + tid;
            int srow = idx >> 5;
            int col8 = (idx & 31) * 8;
            f16x8 x = *(const f16x8*)(src + (size_t)srow * 4096 + col8);
            char* lp = Ls + srow * 516 + col8 * 2;
            *(f16x2*)(lp)      = f16x2{x[0], x[1]};
            *(f16x2*)(lp + 4)  = f16x2{x[2], x[3]};
            *(f16x2*)(lp + 8)  = f16x2{x[4], x[5]};
            *(f16x2*)(lp + 12) = f16x2{x[6], x[7]};
        }
        __syncthreads();
        f16* dst = vt + ((size_t)(by * 256) * 2048) + s0;
#pragma unroll
        for (int p = 0; p < 8; ++p) {
            int d = p * 32 + (tid >> 3);
            int s8 = (tid & 7) * 8;
            f16x8 o;
#pragma unroll
            for (int j = 0; j < 8; ++j)
                o[j] = *(const f16*)(Ls + (s8 + j) * 516 + d * 2);
            *(f16x8*)(dst + (size_t)d * 2048 + s8) = o;
        }
    }
}

// ============ fused scores+softcap+mask+softmax+probs-write+PV ==============
__global__ __launch_bounds__(256) void attn_fused(const f16* __restrict__ qr, const f16* __restrict__ kr,
                                                  const f16* __restrict__ vt, float* __restrict__ probs,
                                                  f16* __restrict__ attn) {
    int qt = blockIdx.x, bh = blockIdx.y;
    int b = bh >> 3, h = bh & 7;
    int tid = threadIdx.x, lane = tid & 63, w = tid >> 6;
    int g = lane >> 4;
    __shared__ __align__(16) char lds[73728];   // 2x32KB K/V dbuf + 8KB P
    char* plb = lds + 65536;

    const f16* qbase = qr + ((size_t)bh * 2048 + qt * 64 + w * 16 + (lane & 15)) * 256 + g * 8;
    f16x8 af[8];
#pragma unroll
    for (int ks = 0; ks < 8; ++ks) af[ks] = *(const f16x8*)(qbase + ks * 32);

    const int kt_first = (qt >= 8) ? 0 : (8 - qt);
    const f16* kb0 = kr + ((size_t)((b * 4 + (h >> 1)) * 2048)) * 256;

#define KSTAGE(kta_, par_)                                                    \
    {                                                                         \
        const f16* kb_ = kb0 + (size_t)(kta_) * 16384;                        \
        char* db_ = lds + (par_) * 32768;                                     \
        _Pragma("unroll")                                                     \
        for (int is = 0; is < 8; ++is) {                                      \
            int off = is * 4096 + w * 1024 + lane * 16;                       \
            int row = off >> 9;                                               \
            int sb = (off & 511) ^ ((row & 7) << 4);                          \
            gld16(kb_ + row * 256 + (sb >> 1), db_ + off);                    \
        }                                                                     \
    }

    KSTAGE(qt - 8 + kt_first, kt_first & 1)
    f32x4 acc[9][4] = {};
#pragma unroll
    for (int kt = 0; kt < 9; ++kt) {
        int kta = qt - 8 + kt;
        if (kta >= 0) {
            if (kt < 8) {
                KSTAGE(kta + 1, (kt + 1) & 1)
                asm volatile("s_waitcnt vmcnt(8)" ::: "memory");
            } else {
                asm volatile("s_waitcnt vmcnt(0)" ::: "memory");
            }
            __builtin_amdgcn_s_barrier();
            __builtin_amdgcn_sched_barrier(0);
            const char* kbuf = lds + (kt & 1) * 32768;
            __builtin_amdgcn_s_setprio(1);
#pragma unroll
            for (int n = 0; n < 4; ++n) {
                int row2 = n * 16 + (lane & 15);
#pragma unroll
                for (int ks = 0; ks < 8; ++ks) {
                    int cb = (ks * 64 + g * 16) ^ ((row2 & 7) << 4);
                    f16x8 bfr = *(const f16x8*)(kbuf + row2 * 512 + cb);
                    acc[kt][n] = MFMA16(af[ks], bfr, acc[kt][n]);
                }
            }
            __builtin_amdgcn_s_setprio(0);
            __builtin_amdgcn_s_barrier();
        }
    }

    int row_l = w * 16 + (g << 2);
    int row_g0 = qt * 64 + row_l;
    f32x4 mx = {-1e30f, -1e30f, -1e30f, -1e30f};
#pragma unroll
    for (int kt = 0; kt < 9; ++kt) {
        int kta = qt - 8 + kt;
#pragma unroll
        for (int n = 0; n < 4; ++n) {
            int col = kta * 64 + n * 16 + (lane & 15);
#pragma unroll
            for (int r = 0; r < 4; ++r) {
                float s = acc[kt][n][r] * 0.0625f;
                float t = __expf(s * 0.04f);
                float v = 50.0f * (t - 1.0f) / (t + 1.0f);
                int rowg = row_g0 + r;
                bool ok = (kta >= 0) && (col <= rowg) && (rowg - col < 512);
                float pv_ = ok ? v : -1e9f;
                acc[kt][n][r] = pv_;
                mx[r] = fmaxf(mx[r], pv_);
            }
        }
    }
#pragma unroll
    for (int o = 1; o < 16; o <<= 1) {
#pragma unroll
        for (int r = 0; r < 4; ++r) mx[r] = fmaxf(mx[r], __shfl_xor(mx[r], o, 64));
    }
    f32x4 sm = {0.f, 0.f, 0.f, 0.f};
#pragma unroll
    for (int kt = 0; kt < 9; ++kt)
#pragma unroll
        for (int n = 0; n < 4; ++n)
#pragma unroll
            for (int r = 0; r < 4; ++r) {
                float e = __expf(acc[kt][n][r] - mx[r]);
                acc[kt][n][r] = e;
                sm[r] += e;
            }
#pragma unroll
    for (int o = 1; o < 16; o <<= 1) {
#pragma unroll
        for (int r = 0; r < 4; ++r) sm[r] += __shfl_xor(sm[r], o, 64);
    }
    f32x4 inv;
#pragma unroll
    for (int r = 0; r < 4; ++r) inv[r] = 1.0f / sm[r];
    f16x4 ph[9][4];
#pragma unroll
    for (int kt = 0; kt < 9; ++kt)
#pragma unroll
        for (int n = 0; n < 4; ++n)
#pragma unroll
            for (int r = 0; r < 4; ++r)
                ph[kt][n][r] = (f16)(acc[kt][n][r] * inv[r]);

    const f16* vtb = vt + (size_t)((b * 4 + (h >> 1)) * 256) * 2048;

#define VSTAGE(kta_, par_)                                                    \
    {                                                                         \
        char* db_ = lds + (par_) * 32768;                                     \
        _Pragma("unroll")                                                     \
        for (int is = 0; is < 8; ++is) {                                      \
            int off = is * 4096 + w * 1024 + lane * 16;                       \
            int d = off >> 7;                                                 \
            int sb = (off & 127) ^ ((d & 7) << 4);                            \
            gld16(vtb + (size_t)d * 2048 + (kta_) * 64 + (sb >> 1), db_ + off); \
        }                                                                     \
    }

    VSTAGE(qt - 8 + kt_first, kt_first & 1)
    f32x4 pacc[16] = {};
#pragma unroll
    for (int kt = 0; kt < 9; ++kt) {
        int kta = qt - 8 + kt;
        if (kta >= 0) {
            if (kt < 8) VSTAGE(kta + 1, (kt + 1) & 1)
#pragma unroll
            for (int n = 0; n < 4; ++n)
#pragma unroll
                for (int r = 0; r < 4; ++r) {
                    int row = row_l + r;
                    int cb = (n * 16 + (lane & 15)) * 2;
                    *(f16*)(plb + row * 128 + (cb ^ ((row & 7) << 4))) = ph[kt][n][r];
                }
            if (kt < 8) {
                asm volatile("s_waitcnt vmcnt(8) lgkmcnt(0)" ::: "memory");
            } else {
                asm volatile("s_waitcnt vmcnt(0) lgkmcnt(0)" ::: "memory");
            }
            __builtin_amdgcn_s_barrier();
            __builtin_amdgcn_sched_barrier(0);
            // probs band stores — non-temporal (write-once, drain under MFMA)
#pragma unroll
            for (int n = 0; n < 4; ++n) {
                int col = kta * 64 + n * 16 + (lane & 15);
#pragma unroll
                for (int r = 0; r < 4; ++r)
                    __builtin_nontemporal_store((float)ph[kt][n][r],
                        &probs[((size_t)bh * 2048 + row_g0 + r) * 2048 + col]);
            }
            const char* vbuf = lds + (kt & 1) * 32768;
            int rowp = w * 16 + (lane & 15);
            int pswz = (rowp & 7) << 4;
            f16x8 a0 = *(const f16x8*)(plb + rowp * 128 + ((g * 16) ^ pswz));
            f16x8 a1 = *(const f16x8*)(plb + rowp * 128 + ((g * 16 + 64) ^ pswz));
            __builtin_amdgcn_s_setprio(1);
#pragma unroll
            for (int n = 0; n < 16; ++n) {
                int d = n * 16 + (lane & 15);
                int vswz = (d & 7) << 4;
                f16x8 b0 = *(const f16x8*)(vbuf + d * 128 + ((g * 16) ^ vswz));
                f16x8 b1 = *(const f16x8*)(vbuf + d * 128 + ((g * 16 + 64) ^ vswz));
                pacc[n] = MFMA16(a0, b0, pacc[n]);
                pacc[n] = MFMA16(a1, b1, pacc[n]);
            }
            __builtin_amdgcn_s_setprio(0);
            __builtin_amdgcn_s_barrier();
        }
    }
#undef KSTAGE
#undef VSTAGE

    int kt0 = qt > 8 ? qt - 8 : 0;
    int pre = kt0 * 64;
    int suf = (qt + 1) * 64;
    f32x4 z4 = {0.f, 0.f, 0.f, 0.f};
    for (int r = 0; r < 16; ++r) {
        float* rp = probs + ((size_t)bh * 2048 + qt * 64 + w * 16 + r) * 2048;
        for (int off = lane * 4; off < pre; off += 256)
            __builtin_nontemporal_store(z4, (f32x4*)(rp + off));
        for (int off = suf + lane * 4; off < 2048; off += 256)
            __builtin_nontemporal_store(z4, (f32x4*)(rp + off));
    }

    size_t obase = ((size_t)b * 2048 + qt * 64 + row_l) * 2048 + h * 256;
#pragma unroll
    for (int n = 0; n < 16; ++n) {
        int col = n * 16 + (lane & 15);
#pragma unroll
        for (int r = 0; r < 4; ++r)
            attn[obase + (size_t)r * 2048 + col] = (f16)pacc[n][r];
    }
}

extern "C" void kernel_launch(void* const* d_in, const int* in_sizes, int n_in,
                              void* d_out, int out_size, void* d_ws, size_t ws_size,
                              hipStream_t stream) {
    (void)in_sizes; (void)n_in; (void)out_size; (void)ws_size;
    const float* hs   = (const float*)d_in[0];
    const float* cosb = (const float*)d_in[1];
    const float* sinb = (const float*)d_in[2];
    const float* qw   = (const float*)d_in[4];
    const float* kw   = (const float*)d_in[5];
    const float* vw   = (const float*)d_in[6];
    const float* ow   = (const float*)d_in[7];
    const float* qnw  = (const float*)d_in[8];
    const float* knw  = (const float*)d_in[9];

    float* out = (float*)d_out;
    float* probs = out + (size_t)2 * 2048 * 2560;          // output 1

    char* ws = (char*)d_ws;
    f16* hsb  = (f16*)(ws);                                // 20,971,520 B
    f16* wqkv = (f16*)(ws + 20971520);                     // 20,971,520 B
    f16* owb  = (f16*)(ws + 41943040);                     // 10,485,760 B
    f16* qkvh = (f16*)(ws + 52428800);                     // 33,554,432 B
    f16* qr   = (f16*)(ws + 85983232);                     // 16,777,216 B
    f16* kr   = (f16*)(ws + 102760448);                    //  8,388,608 B
    f16* vt   = (f16*)(ws + 111149056);                    //  8,388,608 B
    f16* attn = (f16*)(ws + 119537664);                    // 16,777,216 B

    // all fp32 -> fp16 casts in one launch
    cvt_all<<<12800, 256, 0, stream>>>(hs, qw, kw, vw, ow, hsb, wqkv, owb);

    // fused QKV projection: 256^2 BK=64 counted-vmcnt pipeline, f16 out
    gemm256<2560, 4096, 16, true><<<256, 512, 0, stream>>>(hsb, wqkv, qkvh);

    // merged RMSNorm+RoPE + V transpose (one launch)
    rmsvt_k<<<12544, 256, 0, stream>>>(qkvh, cosb, sinb, qnw, knw, qr, kr, vt);

    // fused scores+softmax+probs+PV (dbuf K/V, counted vmcnt, NT probs stores)
    attn_fused<<<dim3(32, 16), 256, 0, stream>>>(qr, kr, vt, probs, attn);

    // O projection: 256^2 BK=64 counted-vmcnt pipeline, NT f32 out (output 0)
    gemm256<2048, 2560, 10, false><<<160, 512, 0, stream>>>(attn, owb, out);
}

// Round 12
// 282.129 us; speedup vs baseline: 1.0260x; 1.0260x over previous
//
#include <hip/hip_runtime.h>

typedef _Float16 f16;
typedef float f32x4 __attribute__((ext_vector_type(4)));
typedef _Float16 f16x8 __attribute__((ext_vector_type(8)));
typedef _Float16 f16x4 __attribute__((ext_vector_type(4)));
typedef _Float16 f16x2 __attribute__((ext_vector_type(2)));

#define MFMA16(a, b, c) __builtin_amdgcn_mfma_f32_16x16x32_f16((a), (b), (c), 0, 0, 0)

__device__ __forceinline__ void gld16(const void* g, void* l) {
    __builtin_amdgcn_global_load_lds((const __attribute__((address_space(1))) unsigned int*)g,
                                     (__attribute__((address_space(3))) unsigned int*)l, 16, 0, 0);
}

// ---------------- merged fp32 -> fp16 cast for all 5 tensors ----------------
// NT loads: inputs are read exactly once — keep them out of L2 (read-side
// analog of the round-10 NT-store win).
__global__ __launch_bounds__(256) void cvt_all(const float* __restrict__ hs, const float* __restrict__ qw,
                                               const float* __restrict__ kw, const float* __restrict__ vw,
                                               const float* __restrict__ ow, f16* __restrict__ hsb,
                                               f16* __restrict__ wqkv, f16* __restrict__ owb) {
    long g = (long)(blockIdx.x * 256 + threadIdx.x) * 8;
    const float* src;
    f16* dst;
    long off;
    if (g < 10485760L) { src = hs; dst = hsb; off = g; }
    else if (g < 15728640L) { src = qw; dst = wqkv; off = g - 10485760L; }
    else if (g < 18350080L) { src = kw; dst = wqkv + 5242880; off = g - 15728640L; }
    else if (g < 20971520L) { src = vw; dst = wqkv + 7864320; off = g - 18350080L; }
    else { src = ow; dst = owb; off = g - 20971520L; }
    f32x4 a = __builtin_nontemporal_load((const f32x4*)(src + off));
    f32x4 b = __builtin_nontemporal_load((const f32x4*)(src + off + 4));
    f16x8 o;
    o[0] = (f16)a[0]; o[1] = (f16)a[1]; o[2] = (f16)a[2]; o[3] = (f16)a[3];
    o[4] = (f16)b[0]; o[5] = (f16)b[1]; o[6] = (f16)b[2]; o[7] = (f16)b[3];
    *(f16x8*)(dst + off) = o;
}

// ============ 256x256-tile GEMM, BK=64, 2-buf, 1 barrier/K-tile (T1-T5) =====
// (round-10 drain schedule — the counted-vmcnt variant regressed; T4 is
// schedule-conditional and does not apply to a 1-barrier-per-tile loop)
template <int K, int N, int GN, bool F16OUT>
__global__ __launch_bounds__(512, 1) void gemm256(const f16* __restrict__ A, const f16* __restrict__ W,
                                                  void* __restrict__ Cv) {
    constexpr int NT = K / 64;
    __shared__ __align__(16) char lds[131072];
    const int tid = threadIdx.x;
    const int lane = tid & 63, wid = tid >> 6;
    const int wr = wid >> 2, wc = wid & 3;
    const int g = lane >> 4;
    int bid = blockIdx.x;
    int swz = (bid & 7) * ((16 * GN) >> 3) + (bid >> 3);
    const int m0 = (swz / GN) * 256, n0 = (swz % GN) * 256;

    const int kel = 8 * ((tid & 7) ^ ((tid >> 3) & 7));   // pre-swizzled k (elems)
    const int rowb = tid >> 3;                            // 0..63
    const f16* pA = A + (size_t)(m0 + rowb) * K + kel;
    const f16* pB = W + (size_t)(n0 + rowb) * K + kel;
    const int dst_o = tid * 16;

#define QSTAGE(bi, t)                                                     \
    {                                                                     \
        char* lb_ = lds + (bi) * 65536;                                   \
        int k0_ = (t) * 64;                                               \
        gld16(pA + k0_,                 lb_ + dst_o);                     \
        gld16(pA + (size_t)64 * K + k0_,  lb_ + 8192 + dst_o);            \
        gld16(pA + (size_t)128 * K + k0_, lb_ + 16384 + dst_o);           \
        gld16(pA + (size_t)192 * K + k0_, lb_ + 24576 + dst_o);           \
        gld16(pB + k0_,                 lb_ + 32768 + dst_o);             \
        gld16(pB + (size_t)64 * K + k0_,  lb_ + 40960 + dst_o);           \
        gld16(pB + (size_t)128 * K + k0_, lb_ + 49152 + dst_o);           \
        gld16(pB + (size_t)192 * K + k0_, lb_ + 57344 + dst_o);           \
    }

    const int xorv = (lane & 7) << 4;
    const int arow = wr * 128 + (lane & 15);
    const int brow = wc * 64 + (lane & 15);

    f32x4 acc[8][4] = {};

#define QCOMPUTE(bi)                                                      \
    {                                                                     \
        const char* ab_ = lds + (bi) * 65536;                             \
        const char* bb_ = ab_ + 32768;                                    \
        _Pragma("unroll")                                                 \
        for (int ks = 0; ks < 2; ++ks) {                                  \
            const int cc = (ks * 64 + g * 16) ^ xorv;                     \
            f16x8 Af[8], Bf[4];                                           \
            _Pragma("unroll")                                             \
            for (int m = 0; m < 8; ++m)                                   \
                Af[m] = *(const f16x8*)(ab_ + (arow + m * 16) * 128 + cc);\
            _Pragma("unroll")                                             \
            for (int n = 0; n < 4; ++n)                                   \
                Bf[n] = *(const f16x8*)(bb_ + (brow + n * 16) * 128 + cc);\
            __builtin_amdgcn_s_setprio(1);                                \
            _Pragma("unroll")                                             \
            for (int m = 0; m < 8; ++m)                                   \
                _Pragma("unroll")                                         \
                for (int n = 0; n < 4; ++n)                               \
                    acc[m][n] = MFMA16(Af[m], Bf[n], acc[m][n]);          \
            __builtin_amdgcn_s_setprio(0);                                \
        }                                                                 \
    }

    QSTAGE(0, 0)
    asm volatile("s_waitcnt vmcnt(0)" ::: "memory");
    __builtin_amdgcn_s_barrier();

#pragma unroll 1
    for (int t = 0; t < NT; ++t) {
        if (t + 1 < NT) QSTAGE((t + 1) & 1, t + 1)   // issue-early (T14/T3)
        QCOMPUTE(t & 1)
        asm volatile("s_waitcnt vmcnt(0) lgkmcnt(0)" ::: "memory");
        __builtin_amdgcn_s_barrier();                // one barrier per K-tile
    }

#pragma unroll
    for (int m = 0; m < 8; ++m) {
        int row = m0 + wr * 128 + m * 16 + ((lane >> 4) << 2);
#pragma unroll
        for (int n = 0; n < 4; ++n) {
            int col = n0 + wc * 64 + n * 16 + (lane & 15);
#pragma unroll
            for (int r = 0; r < 4; ++r) {
                if constexpr (F16OUT)
                    ((f16*)Cv)[(size_t)(row + r) * N + col] = (f16)acc[m][n][r];
                else
                    __builtin_nontemporal_store(acc[m][n][r],
                        &((float*)Cv)[(size_t)(row + r) * N + col]);
            }
        }
    }
#undef QSTAGE
#undef QCOMPUTE
}

// ------- merged RMSNorm+RoPE (blocks 0..12287) + V transpose (12288..12543) -
__global__ __launch_bounds__(256) void rmsvt_k(const f16* __restrict__ qkvh,
                                               const float* __restrict__ cosb, const float* __restrict__ sinb,
                                               const float* __restrict__ qnw, const float* __restrict__ knw,
                                               f16* __restrict__ qr, f16* __restrict__ kr,
                                               f16* __restrict__ vt) {
    if (blockIdx.x < 12288) {
        // ---- RMSNorm + RoPE: one wave per (b,s,head) ----
        int wid = threadIdx.x >> 6, lane = threadIdx.x & 63;
        int task = blockIdx.x * 4 + wid;
        int slot = task % 12;
        int bs = task / 12;
        int b = bs >> 11, s = bs & 2047;
        const f16* src;
        const float* w;
        f16* dst;
        if (slot < 8) {
            src = qkvh + (size_t)bs * 4096 + slot * 256;
            w = qnw;
            dst = qr + ((size_t)(b * 8 + slot) * 2048 + s) * 256;
        } else {
            int h = slot - 8;
            src = qkvh + (size_t)bs * 4096 + 2048 + h * 256;
            w = knw;
            dst = kr + ((size_t)(b * 4 + h) * 2048 + s) * 256;
        }
        int i = lane * 4;
        f16x4 xr = *(const f16x4*)(src + i);
        float4 x;
        x.x = (float)xr[0]; x.y = (float)xr[1]; x.z = (float)xr[2]; x.w = (float)xr[3];
        float ss = x.x * x.x + x.y * x.y + x.z * x.z + x.w * x.w;
#pragma unroll
        for (int o = 32; o; o >>= 1) ss += __shfl_xor(ss, o, 64);
        float rs = rsqrtf(ss * (1.0f / 256.0f) + 1e-6f);
        float4 y;
        y.x = __shfl_xor(x.x, 32, 64);
        y.y = __shfl_xor(x.y, 32, 64);
        y.z = __shfl_xor(x.z, 32, 64);
        y.w = __shfl_xor(x.w, 32, 64);
        float4 wv = *(const float4*)(w + i);
        float4 wp = *(const float4*)(w + (i ^ 128));
        float4 c = *(const float4*)(cosb + (size_t)bs * 256 + i);
        float4 sn = *(const float4*)(sinb + (size_t)bs * 256 + i);
        float sgn = (lane < 32) ? -1.0f : 1.0f;
        float n0 = x.x * rs * (1.f + wv.x), n1 = x.y * rs * (1.f + wv.y);
        float n2 = x.z * rs * (1.f + wv.z), n3 = x.w * rs * (1.f + wv.w);
        float r0 = y.x * rs * (1.f + wp.x) * sgn, r1 = y.y * rs * (1.f + wp.y) * sgn;
        float r2 = y.z * rs * (1.f + wp.z) * sgn, r3 = y.w * rs * (1.f + wp.w) * sgn;
        f16x4 outv;
        outv[0] = (f16)(n0 * c.x + r0 * sn.x);
        outv[1] = (f16)(n1 * c.y + r1 * sn.y);
        outv[2] = (f16)(n2 * c.z + r2 * sn.z);
        outv[3] = (f16)(n3 * c.w + r3 * sn.w);
        *(f16x4*)(dst + i) = outv;
    } else {
        // ---- V transpose tile ----
        __shared__ __align__(16) char Ls[64 * 516];
        int tile = blockIdx.x - 12288;   // 0..255
        int st = tile & 31;
        int by = tile >> 5;
        int b = by >> 2, kvh = by & 3;
        int tid = threadIdx.x;
        int s0 = st * 64;
        const f16* src = qkvh + ((size_t)(b * 2048 + s0)) * 4096 + 3072 + kvh * 256;
#pragma unroll
        for (int it = 0; it < 8; ++it) {
            int idx = it * 256 + tid;
            int srow = idx >> 5;
            int col8 = (idx & 31) * 8;
            f16x8 x = *(const f16x8*)(src + (size_t)srow * 4096 + col8);
            char* lp = Ls + srow * 516 + col8 * 2;
            *(f16x2*)(lp)      = f16x2{x[0], x[1]};
            *(f16x2*)(lp + 4)  = f16x2{x[2], x[3]};
            *(f16x2*)(lp + 8)  = f16x2{x[4], x[5]};
            *(f16x2*)(lp + 12) = f16x2{x[6], x[7]};
        }
        __syncthreads();
        f16* dst = vt + ((size_t)(by * 256) * 2048) + s0;
#pragma unroll
        for (int p = 0; p < 8; ++p) {
            int d = p * 32 + (tid >> 3);
            int s8 = (tid & 7) * 8;
            f16x8 o;
#pragma unroll
            for (int j = 0; j < 8; ++j)
                o[j] = *(const f16*)(Ls + (s8 + j) * 516 + d * 2);
            *(f16x8*)(dst + (size_t)d * 2048 + s8) = o;
        }
    }
}

// ============ fused scores+softcap+mask+softmax+probs-write+PV ==============
__global__ __launch_bounds__(256) void attn_fused(const f16* __restrict__ qr, const f16* __restrict__ kr,
                                                  const f16* __restrict__ vt, float* __restrict__ probs,
                                                  f16* __restrict__ attn) {
    int qt = blockIdx.x, bh = blockIdx.y;
    int b = bh >> 3, h = bh & 7;
    int tid = threadIdx.x, lane = tid & 63, w = tid >> 6;
    int g = lane >> 4;
    __shared__ __align__(16) char lds[73728];   // 2x32KB K/V dbuf + 8KB P
    char* plb = lds + 65536;

    const f16* qbase = qr + ((size_t)bh * 2048 + qt * 64 + w * 16 + (lane & 15)) * 256 + g * 8;
    f16x8 af[8];
#pragma unroll
    for (int ks = 0; ks < 8; ++ks) af[ks] = *(const f16x8*)(qbase + ks * 32);

    const int kt_first = (qt >= 8) ? 0 : (8 - qt);
    const f16* kb0 = kr + ((size_t)((b * 4 + (h >> 1)) * 2048)) * 256;

#define KSTAGE(kta_, par_)                                                    \
    {                                                                         \
        const f16* kb_ = kb0 + (size_t)(kta_) * 16384;                        \
        char* db_ = lds + (par_) * 32768;                                     \
        _Pragma("unroll")                                                     \
        for (int is = 0; is < 8; ++is) {                                      \
            int off = is * 4096 + w * 1024 + lane * 16;                       \
            int row = off >> 9;                                               \
            int sb = (off & 511) ^ ((row & 7) << 4);                          \
            gld16(kb_ + row * 256 + (sb >> 1), db_ + off);                    \
        }                                                                     \
    }

    KSTAGE(qt - 8 + kt_first, kt_first & 1)
    f32x4 acc[9][4] = {};
#pragma unroll
    for (int kt = 0; kt < 9; ++kt) {
        int kta = qt - 8 + kt;
        if (kta >= 0) {
            if (kt < 8) {
                KSTAGE(kta + 1, (kt + 1) & 1)
                asm volatile("s_waitcnt vmcnt(8)" ::: "memory");
            } else {
                asm volatile("s_waitcnt vmcnt(0)" ::: "memory");
            }
            __builtin_amdgcn_s_barrier();
            __builtin_amdgcn_sched_barrier(0);
            const char* kbuf = lds + (kt & 1) * 32768;
            __builtin_amdgcn_s_setprio(1);
#pragma unroll
            for (int n = 0; n < 4; ++n) {
                int row2 = n * 16 + (lane & 15);
#pragma unroll
                for (int ks = 0; ks < 8; ++ks) {
                    int cb = (ks * 64 + g * 16) ^ ((row2 & 7) << 4);
                    f16x8 bfr = *(const f16x8*)(kbuf + row2 * 512 + cb);
                    acc[kt][n] = MFMA16(af[ks], bfr, acc[kt][n]);
                }
            }
            __builtin_amdgcn_s_setprio(0);
            __builtin_amdgcn_s_barrier();
        }
    }

    int row_l = w * 16 + (g << 2);
    int row_g0 = qt * 64 + row_l;
    f32x4 mx = {-1e30f, -1e30f, -1e30f, -1e30f};
#pragma unroll
    for (int kt = 0; kt < 9; ++kt) {
        int kta = qt - 8 + kt;
#pragma unroll
        for (int n = 0; n < 4; ++n) {
            int col = kta * 64 + n * 16 + (lane & 15);
#pragma unroll
            for (int r = 0; r < 4; ++r) {
                float s = acc[kt][n][r] * 0.0625f;
                float t = __expf(s * 0.04f);
                float v = 50.0f * (t - 1.0f) / (t + 1.0f);
                int rowg = row_g0 + r;
                bool ok = (kta >= 0) && (col <= rowg) && (rowg - col < 512);
                float pv_ = ok ? v : -1e9f;
                acc[kt][n][r] = pv_;
                mx[r] = fmaxf(mx[r], pv_);
            }
        }
    }
#pragma unroll
    for (int o = 1; o < 16; o <<= 1) {
#pragma unroll
        for (int r = 0; r < 4; ++r) mx[r] = fmaxf(mx[r], __shfl_xor(mx[r], o, 64));
    }
    f32x4 sm = {0.f, 0.f, 0.f, 0.f};
#pragma unroll
    for (int kt = 0; kt < 9; ++kt)
#pragma unroll
        for (int n = 0; n < 4; ++n)
#pragma unroll
            for (int r = 0; r < 4; ++r) {
                float e = __expf(acc[kt][n][r] - mx[r]);
                acc[kt][n][r] = e;
                sm[r] += e;
            }
#pragma unroll
    for (int o = 1; o < 16; o <<= 1) {
#pragma unroll
        for (int r = 0; r < 4; ++r) sm[r] += __shfl_xor(sm[r], o, 64);
    }
    f32x4 inv;
#pragma unroll
    for (int r = 0; r < 4; ++r) inv[r] = 1.0f / sm[r];
    f16x4 ph[9][4];
#pragma unroll
    for (int kt = 0; kt < 9; ++kt)
#pragma unroll
        for (int n = 0; n < 4; ++n)
#pragma unroll
            for (int r = 0; r < 4; ++r)
                ph[kt][n][r] = (f16)(acc[kt][n][r] * inv[r]);

    const f16* vtb = vt + (size_t)((b * 4 + (h >> 1)) * 256) * 2048;

#define VSTAGE(kta_, par_)                                                    \
    {                                                                         \
        char* db_ = lds + (par_) * 32768;                                     \
        _Pragma("unroll")                                                     \
        for (int is = 0; is < 8; ++is) {                                      \
            int off = is * 4096 + w * 1024 + lane * 16;                       \
            int d = off >> 7;                                                 \
            int sb = (off & 127) ^ ((d & 7) << 4);                            \
            gld16(vtb + (size_t)d * 2048 + (kta_) * 64 + (sb >> 1), db_ + off); \
        }                                                                     \
    }

    VSTAGE(qt - 8 + kt_first, kt_first & 1)
    f32x4 pacc[16] = {};
#pragma unroll
    for (int kt = 0; kt < 9; ++kt) {
        int kta = qt - 8 + kt;
        if (kta >= 0) {
            if (kt < 8) VSTAGE(kta + 1, (kt + 1) & 1)
#pragma unroll
            for (int n = 0; n < 4; ++n)
#pragma unroll
                for (int r = 0; r < 4; ++r) {
                    int row = row_l + r;
                    int cb = (n * 16 + (lane & 15)) * 2;
                    *(f16*)(plb + row * 128 + (cb ^ ((row & 7) << 4))) = ph[kt][n][r];
                }
            if (kt < 8) {
                asm volatile("s_waitcnt vmcnt(8) lgkmcnt(0)" ::: "memory");
            } else {
                asm volatile("s_waitcnt vmcnt(0) lgkmcnt(0)" ::: "memory");
            }
            __builtin_amdgcn_s_barrier();
            __builtin_amdgcn_sched_barrier(0);
            // probs band stores — non-temporal (write-once, drain under MFMA)
#pragma unroll
            for (int n = 0; n < 4; ++n) {
                int col = kta * 64 + n * 16 + (lane & 15);
#pragma unroll
                for (int r = 0; r < 4; ++r)
                    __builtin_nontemporal_store((float)ph[kt][n][r],
                        &probs[((size_t)bh * 2048 + row_g0 + r) * 2048 + col]);
            }
            const char* vbuf = lds + (kt & 1) * 32768;
            int rowp = w * 16 + (lane & 15);
            int pswz = (rowp & 7) << 4;
            f16x8 a0 = *(const f16x8*)(plb + rowp * 128 + ((g * 16) ^ pswz));
            f16x8 a1 = *(const f16x8*)(plb + rowp * 128 + ((g * 16 + 64) ^ pswz));
            __builtin_amdgcn_s_setprio(1);
#pragma unroll
            for (int n = 0; n < 16; ++n) {
                int d = n * 16 + (lane & 15);
                int vswz = (d & 7) << 4;
                f16x8 b0 = *(const f16x8*)(vbuf + d * 128 + ((g * 16) ^ vswz));
                f16x8 b1 = *(const f16x8*)(vbuf + d * 128 + ((g * 16 + 64) ^ vswz));
                pacc[n] = MFMA16(a0, b0, pacc[n]);
                pacc[n] = MFMA16(a1, b1, pacc[n]);
            }
            __builtin_amdgcn_s_setprio(0);
            __builtin_amdgcn_s_barrier();
        }
    }
#undef KSTAGE
#undef VSTAGE

    int kt0 = qt > 8 ? qt - 8 : 0;
    int pre = kt0 * 64;
    int suf = (qt + 1) * 64;
    f32x4 z4 = {0.f, 0.f, 0.f, 0.f};
    for (int r = 0; r < 16; ++r) {
        float* rp = probs + ((size_t)bh * 2048 + qt * 64 + w * 16 + r) * 2048;
        for (int off = lane * 4; off < pre; off += 256)
            __builtin_nontemporal_store(z4, (f32x4*)(rp + off));
        for (int off = suf + lane * 4; off < 2048; off += 256)
            __builtin_nontemporal_store(z4, (f32x4*)(rp + off));
    }

    size_t obase = ((size_t)b * 2048 + qt * 64 + row_l) * 2048 + h * 256;
#pragma unroll
    for (int n = 0; n < 16; ++n) {
        int col = n * 16 + (lane & 15);
#pragma unroll
        for (int r = 0; r < 4; ++r)
            attn[obase + (size_t)r * 2048 + col] = (f16)pacc[n][r];
    }
}

extern "C" void kernel_launch(void* const* d_in, const int* in_sizes, int n_in,
                              void* d_out, int out_size, void* d_ws, size_t ws_size,
                              hipStream_t stream) {
    (void)in_sizes; (void)n_in; (void)out_size; (void)ws_size;
    const float* hs   = (const float*)d_in[0];
    const float* cosb = (const float*)d_in[1];
    const float* sinb = (const float*)d_in[2];
    const float* qw   = (const float*)d_in[4];
    const float* kw   = (const float*)d_in[5];
    const float* vw   = (const float*)d_in[6];
    const float* ow   = (const float*)d_in[7];
    const float* qnw  = (const float*)d_in[8];
    const float* knw  = (const float*)d_in[9];

    float* out = (float*)d_out;
    float* probs = out + (size_t)2 * 2048 * 2560;          // output 1

    char* ws = (char*)d_ws;
    f16* hsb  = (f16*)(ws);                                // 20,971,520 B
    f16* wqkv = (f16*)(ws + 20971520);                     // 20,971,520 B
    f16* owb  = (f16*)(ws + 41943040);                     // 10,485,760 B
    f16* qkvh = (f16*)(ws + 52428800);                     // 33,554,432 B
    f16* qr   = (f16*)(ws + 85983232);                     // 16,777,216 B
    f16* kr   = (f16*)(ws + 102760448);                    //  8,388,608 B
    f16* vt   = (f16*)(ws + 111149056);                    //  8,388,608 B
    f16* attn = (f16*)(ws + 119537664);                    // 16,777,216 B

    // all fp32 -> fp16 casts in one launch (NT loads)
    cvt_all<<<12800, 256, 0, stream>>>(hs, qw, kw, vw, ow, hsb, wqkv, owb);

    // fused QKV projection: 256^2 BK=64 single-barrier pipeline, f16 out
    gemm256<2560, 4096, 16, true><<<256, 512, 0, stream>>>(hsb, wqkv, qkvh);

    // merged RMSNorm+RoPE + V transpose (one launch)
    rmsvt_k<<<12544, 256, 0, stream>>>(qkvh, cosb, sinb, qnw, knw, qr, kr, vt);

    // fused scores+softmax+probs+PV (dbuf K/V, counted vmcnt, NT probs stores)
    attn_fused<<<dim3(32, 16), 256, 0, stream>>>(qr, kr, vt, probs, attn);

    // O projection: 256^2 BK=64 single-barrier pipeline, NT f32 out (output 0)
    gemm256<2048, 2560, 10, false><<<160, 512, 0, stream>>>(attn, owb, out);
}

// Round 13
// 276.900 us; speedup vs baseline: 1.0454x; 1.0189x over previous
//
#include <hip/hip_runtime.h>

typedef _Float16 f16;
typedef float f32x4 __attribute__((ext_vector_type(4)));
typedef _Float16 f16x8 __attribute__((ext_vector_type(8)));
typedef _Float16 f16x4 __attribute__((ext_vector_type(4)));
typedef _Float16 f16x2 __attribute__((ext_vector_type(2)));

#define MFMA16(a, b, c) __builtin_amdgcn_mfma_f32_16x16x32_f16((a), (b), (c), 0, 0, 0)

__device__ __forceinline__ void gld16(const void* g, void* l) {
    __builtin_amdgcn_global_load_lds((const __attribute__((address_space(1))) unsigned int*)g,
                                     (__attribute__((address_space(3))) unsigned int*)l, 16, 0, 0);
}

// ---------------- merged fp32 -> fp16 cast for all 5 tensors ----------------
__global__ __launch_bounds__(256) void cvt_all(const float* __restrict__ hs, const float* __restrict__ qw,
                                               const float* __restrict__ kw, const float* __restrict__ vw,
                                               const float* __restrict__ ow, f16* __restrict__ hsb,
                                               f16* __restrict__ wqkv, f16* __restrict__ owb) {
    long g = (long)(blockIdx.x * 256 + threadIdx.x) * 8;
    const float* src;
    f16* dst;
    long off;
    if (g < 10485760L) { src = hs; dst = hsb; off = g; }
    else if (g < 15728640L) { src = qw; dst = wqkv; off = g - 10485760L; }
    else if (g < 18350080L) { src = kw; dst = wqkv + 5242880; off = g - 15728640L; }
    else if (g < 20971520L) { src = vw; dst = wqkv + 7864320; off = g - 18350080L; }
    else { src = ow; dst = owb; off = g - 20971520L; }
    float4 a = *(const float4*)(src + off);
    float4 b = *(const float4*)(src + off + 4);
    f16x8 o;
    o[0] = (f16)a.x; o[1] = (f16)a.y; o[2] = (f16)a.z; o[3] = (f16)a.w;
    o[4] = (f16)b.x; o[5] = (f16)b.y; o[6] = (f16)b.z; o[7] = (f16)b.w;
    *(f16x8*)(dst + off) = o;
}

// ============ 256x256-tile GEMM, BK=64, 2-buf, 1 barrier/K-tile (T1-T5) =====
template <int K, int N, int GN, bool F16OUT>
__global__ __launch_bounds__(512, 1) void gemm256(const f16* __restrict__ A, const f16* __restrict__ W,
                                                  void* __restrict__ Cv) {
    constexpr int NT = K / 64;
    __shared__ __align__(16) char lds[131072];
    const int tid = threadIdx.x;
    const int lane = tid & 63, wid = tid >> 6;
    const int wr = wid >> 2, wc = wid & 3;
    const int g = lane >> 4;
    int bid = blockIdx.x;
    int swz = (bid & 7) * ((16 * GN) >> 3) + (bid >> 3);
    const int m0 = (swz / GN) * 256, n0 = (swz % GN) * 256;

    const int kel = 8 * ((tid & 7) ^ ((tid >> 3) & 7));   // pre-swizzled k (elems)
    const int rowb = tid >> 3;                            // 0..63
    const f16* pA = A + (size_t)(m0 + rowb) * K + kel;
    const f16* pB = W + (size_t)(n0 + rowb) * K + kel;
    const int dst_o = tid * 16;

#define QSTAGE(bi, t)                                                     \
    {                                                                     \
        char* lb_ = lds + (bi) * 65536;                                   \
        int k0_ = (t) * 64;                                               \
        gld16(pA + k0_,                 lb_ + dst_o);                     \
        gld16(pA + (size_t)64 * K + k0_,  lb_ + 8192 + dst_o);            \
        gld16(pA + (size_t)128 * K + k0_, lb_ + 16384 + dst_o);           \
        gld16(pA + (size_t)192 * K + k0_, lb_ + 24576 + dst_o);           \
        gld16(pB + k0_,                 lb_ + 32768 + dst_o);             \
        gld16(pB + (size_t)64 * K + k0_,  lb_ + 40960 + dst_o);           \
        gld16(pB + (size_t)128 * K + k0_, lb_ + 49152 + dst_o);           \
        gld16(pB + (size_t)192 * K + k0_, lb_ + 57344 + dst_o);           \
    }

    const int xorv = (lane & 7) << 4;
    const int arow = wr * 128 + (lane & 15);
    const int brow = wc * 64 + (lane & 15);

    f32x4 acc[8][4] = {};

#define QCOMPUTE(bi)                                                      \
    {                                                                     \
        const char* ab_ = lds + (bi) * 65536;                             \
        const char* bb_ = ab_ + 32768;                                    \
        _Pragma("unroll")                                                 \
        for (int ks = 0; ks < 2; ++ks) {                                  \
            const int cc = (ks * 64 + g * 16) ^ xorv;                     \
            f16x8 Af[8], Bf[4];                                           \
            _Pragma("unroll")                                             \
            for (int m = 0; m < 8; ++m)                                   \
                Af[m] = *(const f16x8*)(ab_ + (arow + m * 16) * 128 + cc);\
            _Pragma("unroll")                                             \
            for (int n = 0; n < 4; ++n)                                   \
                Bf[n] = *(const f16x8*)(bb_ + (brow + n * 16) * 128 + cc);\
            __builtin_amdgcn_s_setprio(1);                                \
            _Pragma("unroll")                                             \
            for (int m = 0; m < 8; ++m)                                   \
                _Pragma("unroll")                                         \
                for (int n = 0; n < 4; ++n)                               \
                    acc[m][n] = MFMA16(Af[m], Bf[n], acc[m][n]);          \
            __builtin_amdgcn_s_setprio(0);                                \
        }                                                                 \
    }

    QSTAGE(0, 0)
    asm volatile("s_waitcnt vmcnt(0)" ::: "memory");
    __builtin_amdgcn_s_barrier();

#pragma unroll 1
    for (int t = 0; t < NT; ++t) {
        if (t + 1 < NT) QSTAGE((t + 1) & 1, t + 1)   // issue-early (T14/T3)
        QCOMPUTE(t & 1)
        asm volatile("s_waitcnt vmcnt(0) lgkmcnt(0)" ::: "memory");
        __builtin_amdgcn_s_barrier();                // one barrier per K-tile
    }

#pragma unroll
    for (int m = 0; m < 8; ++m) {
        int row = m0 + wr * 128 + m * 16 + ((lane >> 4) << 2);
#pragma unroll
        for (int n = 0; n < 4; ++n) {
            int col = n0 + wc * 64 + n * 16 + (lane & 15);
#pragma unroll
            for (int r = 0; r < 4; ++r) {
                if constexpr (F16OUT)
                    ((f16*)Cv)[(size_t)(row + r) * N + col] = (f16)acc[m][n][r];
                else
                    __builtin_nontemporal_store(acc[m][n][r],
                        &((float*)Cv)[(size_t)(row + r) * N + col]);
            }
        }
    }
#undef QSTAGE
#undef QCOMPUTE
}

// ------- merged RMSNorm+RoPE (blocks 0..12287) + V transpose (12288..12543) -
__global__ __launch_bounds__(256) void rmsvt_k(const f16* __restrict__ qkvh,
                                               const float* __restrict__ cosb, const float* __restrict__ sinb,
                                               const float* __restrict__ qnw, const float* __restrict__ knw,
                                               f16* __restrict__ qr, f16* __restrict__ kr,
                                               f16* __restrict__ vt) {
    if (blockIdx.x < 12288) {
        // ---- RMSNorm + RoPE: one wave per (b,s,head) ----
        int wid = threadIdx.x >> 6, lane = threadIdx.x & 63;
        int task = blockIdx.x * 4 + wid;
        int slot = task % 12;
        int bs = task / 12;
        int b = bs >> 11, s = bs & 2047;
        const f16* src;
        const float* w;
        f16* dst;
        if (slot < 8) {
            src = qkvh + (size_t)bs * 4096 + slot * 256;
            w = qnw;
            dst = qr + ((size_t)(b * 8 + slot) * 2048 + s) * 256;
        } else {
            int h = slot - 8;
            src = qkvh + (size_t)bs * 4096 + 2048 + h * 256;
            w = knw;
            dst = kr + ((size_t)(b * 4 + h) * 2048 + s) * 256;
        }
        int i = lane * 4;
        f16x4 xr = *(const f16x4*)(src + i);
        float4 x;
        x.x = (float)xr[0]; x.y = (float)xr[1]; x.z = (float)xr[2]; x.w = (float)xr[3];
        float ss = x.x * x.x + x.y * x.y + x.z * x.z + x.w * x.w;
#pragma unroll
        for (int o = 32; o; o >>= 1) ss += __shfl_xor(ss, o, 64);
        float rs = rsqrtf(ss * (1.0f / 256.0f) + 1e-6f);
        float4 y;
        y.x = __shfl_xor(x.x, 32, 64);
        y.y = __shfl_xor(x.y, 32, 64);
        y.z = __shfl_xor(x.z, 32, 64);
        y.w = __shfl_xor(x.w, 32, 64);
        float4 wv = *(const float4*)(w + i);
        float4 wp = *(const float4*)(w + (i ^ 128));
        float4 c = *(const float4*)(cosb + (size_t)bs * 256 + i);
        float4 sn = *(const float4*)(sinb + (size_t)bs * 256 + i);
        float sgn = (lane < 32) ? -1.0f : 1.0f;
        float n0 = x.x * rs * (1.f + wv.x), n1 = x.y * rs * (1.f + wv.y);
        float n2 = x.z * rs * (1.f + wv.z), n3 = x.w * rs * (1.f + wv.w);
        float r0 = y.x * rs * (1.f + wp.x) * sgn, r1 = y.y * rs * (1.f + wp.y) * sgn;
        float r2 = y.z * rs * (1.f + wp.z) * sgn, r3 = y.w * rs * (1.f + wp.w) * sgn;
        f16x4 outv;
        outv[0] = (f16)(n0 * c.x + r0 * sn.x);
        outv[1] = (f16)(n1 * c.y + r1 * sn.y);
        outv[2] = (f16)(n2 * c.z + r2 * sn.z);
        outv[3] = (f16)(n3 * c.w + r3 * sn.w);
        *(f16x4*)(dst + i) = outv;
    } else {
        // ---- V transpose tile ----
        __shared__ __align__(16) char Ls[64 * 516];
        int tile = blockIdx.x - 12288;   // 0..255
        int st = tile & 31;
        int by = tile >> 5;
        int b = by >> 2, kvh = by & 3;
        int tid = threadIdx.x;
        int s0 = st * 64;
        const f16* src = qkvh + ((size_t)(b * 2048 + s0)) * 4096 + 3072 + kvh * 256;
#pragma unroll
        for (int it = 0; it < 8; ++it) {
            int idx = it * 256 + tid;
            int srow = idx >> 5;
            int col8 = (idx & 31) * 8;
            f16x8 x = *(const f16x8*)(src + (size_t)srow * 4096 + col8);
            char* lp = Ls + srow * 516 + col8 * 2;
            *(f16x2*)(lp)      = f16x2{x[0], x[1]};
            *(f16x2*)(lp + 4)  = f16x2{x[2], x[3]};
            *(f16x2*)(lp + 8)  = f16x2{x[4], x[5]};
            *(f16x2*)(lp + 12) = f16x2{x[6], x[7]};
        }
        __syncthreads();
        f16* dst = vt + ((size_t)(by * 256) * 2048) + s0;
#pragma unroll
        for (int p = 0; p < 8; ++p) {
            int d = p * 32 + (tid >> 3);
            int s8 = (tid & 7) * 8;
            f16x8 o;
#pragma unroll
            for (int j = 0; j < 8; ++j)
                o[j] = *(const f16*)(Ls + (s8 + j) * 516 + d * 2);
            *(f16x8*)(dst + (size_t)d * 2048 + s8) = o;
        }
    }
}

// ============ fused scores+softcap+mask+softmax+probs-write+PV ==============
__global__ __launch_bounds__(256) void attn_fused(const f16* __restrict__ qr, const f16* __restrict__ kr,
                                                  const f16* __restrict__ vt, float* __restrict__ probs,
                                                  f16* __restrict__ attn) {
    int qt = blockIdx.x, bh = blockIdx.y;
    int b = bh >> 3, h = bh & 7;
    int tid = threadIdx.x, lane = tid & 63, w = tid >> 6;
    int g = lane >> 4;
    __shared__ __align__(16) char lds[73728];   // 2x32KB K/V dbuf + 8KB P
    char* plb = lds + 65536;

    const f16* qbase = qr + ((size_t)bh * 2048 + qt * 64 + w * 16 + (lane & 15)) * 256 + g * 8;
    f16x8 af[8];
#pragma unroll
    for (int ks = 0; ks < 8; ++ks) af[ks] = *(const f16x8*)(qbase + ks * 32);

    const int kt_first = (qt >= 8) ? 0 : (8 - qt);
    const f16* kb0 = kr + ((size_t)((b * 4 + (h >> 1)) * 2048)) * 256;

#define KSTAGE(kta_, par_)                                                    \
    {                                                                         \
        const f16* kb_ = kb0 + (size_t)(kta_) * 16384;                        \
        char* db_ = lds + (par_) * 32768;                                     \
        _Pragma("unroll")                                                     \
        for (int is = 0; is < 8; ++is) {                                      \
            int off = is * 4096 + w * 1024 + lane * 16;                       \
            int row = off >> 9;                                               \
            int sb = (off & 511) ^ ((row & 7) << 4);                          \
            gld16(kb_ + row * 256 + (sb >> 1), db_ + off);                    \
        }                                                                     \
    }

    KSTAGE(qt - 8 + kt_first, kt_first & 1)
    f32x4 acc[9][4] = {};
#pragma unroll
    for (int kt = 0; kt < 9; ++kt) {
        int kta = qt - 8 + kt;
        if (kta >= 0) {
            if (kt < 8) {
                KSTAGE(kta + 1, (kt + 1) & 1)
                asm volatile("s_waitcnt vmcnt(8)" ::: "memory");
            } else {
                asm volatile("s_waitcnt vmcnt(0)" ::: "memory");
            }
            __builtin_amdgcn_s_barrier();
            __builtin_amdgcn_sched_barrier(0);
            const char* kbuf = lds + (kt & 1) * 32768;
            __builtin_amdgcn_s_setprio(1);
#pragma unroll
            for (int n = 0; n < 4; ++n) {
                int row2 = n * 16 + (lane & 15);
#pragma unroll
                for (int ks = 0; ks < 8; ++ks) {
                    int cb = (ks * 64 + g * 16) ^ ((row2 & 7) << 4);
                    f16x8 bfr = *(const f16x8*)(kbuf + row2 * 512 + cb);
                    acc[kt][n] = MFMA16(af[ks], bfr, acc[kt][n]);
                }
            }
            __builtin_amdgcn_s_setprio(0);
            __builtin_amdgcn_s_barrier();
        }
    }

    int row_l = w * 16 + (g << 2);
    int row_g0 = qt * 64 + row_l;
    f32x4 mx = {-1e30f, -1e30f, -1e30f, -1e30f};
#pragma unroll
    for (int kt = 0; kt < 9; ++kt) {
        int kta = qt - 8 + kt;
#pragma unroll
        for (int n = 0; n < 4; ++n) {
            int col = kta * 64 + n * 16 + (lane & 15);
#pragma unroll
            for (int r = 0; r < 4; ++r) {
                float s = acc[kt][n][r] * 0.0625f;
                float t = __expf(s * 0.04f);
                float v = 50.0f * (t - 1.0f) / (t + 1.0f);
                int rowg = row_g0 + r;
                bool ok = (kta >= 0) && (col <= rowg) && (rowg - col < 512);
                float pv_ = ok ? v : -1e9f;
                acc[kt][n][r] = pv_;
                mx[r] = fmaxf(mx[r], pv_);
            }
        }
    }
#pragma unroll
    for (int o = 1; o < 16; o <<= 1) {
#pragma unroll
        for (int r = 0; r < 4; ++r) mx[r] = fmaxf(mx[r], __shfl_xor(mx[r], o, 64));
    }
    f32x4 sm = {0.f, 0.f, 0.f, 0.f};
#pragma unroll
    for (int kt = 0; kt < 9; ++kt)
#pragma unroll
        for (int n = 0; n < 4; ++n)
#pragma unroll
            for (int r = 0; r < 4; ++r) {
                float e = __expf(acc[kt][n][r] - mx[r]);
                acc[kt][n][r] = e;
                sm[r] += e;
            }
#pragma unroll
    for (int o = 1; o < 16; o <<= 1) {
#pragma unroll
        for (int r = 0; r < 4; ++r) sm[r] += __shfl_xor(sm[r], o, 64);
    }
    f32x4 inv;
#pragma unroll
    for (int r = 0; r < 4; ++r) inv[r] = 1.0f / sm[r];
    f16x4 ph[9][4];
#pragma unroll
    for (int kt = 0; kt < 9; ++kt)
#pragma unroll
        for (int n = 0; n < 4; ++n)
#pragma unroll
            for (int r = 0; r < 4; ++r)
                ph[kt][n][r] = (f16)(acc[kt][n][r] * inv[r]);

    const f16* vtb = vt + (size_t)((b * 4 + (h >> 1)) * 256) * 2048;

#define VSTAGE(kta_, par_)                                                    \
    {                                                                         \
        char* db_ = lds + (par_) * 32768;                                     \
        _Pragma("unroll")                                                     \
        for (int is = 0; is < 8; ++is) {                                      \
            int off = is * 4096 + w * 1024 + lane * 16;                       \
            int d = off >> 7;                                                 \
            int sb = (off & 127) ^ ((d & 7) << 4);                            \
            gld16(vtb + (size_t)d * 2048 + (kta_) * 64 + (sb >> 1), db_ + off); \
        }                                                                     \
    }

    VSTAGE(qt - 8 + kt_first, kt_first & 1)
    f32x4 pacc[16] = {};
#pragma unroll
    for (int kt = 0; kt < 9; ++kt) {
        int kta = qt - 8 + kt;
        if (kta >= 0) {
            if (kt < 8) VSTAGE(kta + 1, (kt + 1) & 1)
#pragma unroll
            for (int n = 0; n < 4; ++n)
#pragma unroll
                for (int r = 0; r < 4; ++r) {
                    int row = row_l + r;
                    int cb = (n * 16 + (lane & 15)) * 2;
                    *(f16*)(plb + row * 128 + (cb ^ ((row & 7) << 4))) = ph[kt][n][r];
                }
            if (kt < 8) {
                asm volatile("s_waitcnt vmcnt(8) lgkmcnt(0)" ::: "memory");
            } else {
                asm volatile("s_waitcnt vmcnt(0) lgkmcnt(0)" ::: "memory");
            }
            __builtin_amdgcn_s_barrier();
            __builtin_amdgcn_sched_barrier(0);
            // probs band stores — non-temporal (write-once, drain under MFMA)
#pragma unroll
            for (int n = 0; n < 4; ++n) {
                int col = kta * 64 + n * 16 + (lane & 15);
#pragma unroll
                for (int r = 0; r < 4; ++r)
                    __builtin_nontemporal_store((float)ph[kt][n][r],
                        &probs[((size_t)bh * 2048 + row_g0 + r) * 2048 + col]);
            }
            const char* vbuf = lds + (kt & 1) * 32768;
            int rowp = w * 16 + (lane & 15);
            int pswz = (rowp & 7) << 4;
            f16x8 a0 = *(const f16x8*)(plb + rowp * 128 + ((g * 16) ^ pswz));
            f16x8 a1 = *(const f16x8*)(plb + rowp * 128 + ((g * 16 + 64) ^ pswz));
            __builtin_amdgcn_s_setprio(1);
#pragma unroll
            for (int n = 0; n < 16; ++n) {
                int d = n * 16 + (lane & 15);
                int vswz = (d & 7) << 4;
                f16x8 b0 = *(const f16x8*)(vbuf + d * 128 + ((g * 16) ^ vswz));
                f16x8 b1 = *(const f16x8*)(vbuf + d * 128 + ((g * 16 + 64) ^ vswz));
                pacc[n] = MFMA16(a0, b0, pacc[n]);
                pacc[n] = MFMA16(a1, b1, pacc[n]);
            }
            __builtin_amdgcn_s_setprio(0);
            __builtin_amdgcn_s_barrier();
        }
    }
#undef KSTAGE
#undef VSTAGE

    int kt0 = qt > 8 ? qt - 8 : 0;
    int pre = kt0 * 64;
    int suf = (qt + 1) * 64;
    f32x4 z4 = {0.f, 0.f, 0.f, 0.f};
    for (int r = 0; r < 16; ++r) {
        float* rp = probs + ((size_t)bh * 2048 + qt * 64 + w * 16 + r) * 2048;
        for (int off = lane * 4; off < pre; off += 256)
            __builtin_nontemporal_store(z4, (f32x4*)(rp + off));
        for (int off = suf + lane * 4; off < 2048; off += 256)
            __builtin_nontemporal_store(z4, (f32x4*)(rp + off));
    }

    size_t obase = ((size_t)b * 2048 + qt * 64 + row_l) * 2048 + h * 256;
#pragma unroll
    for (int n = 0; n < 16; ++n) {
        int col = n * 16 + (lane & 15);
#pragma unroll
        for (int r = 0; r < 4; ++r)
            attn[obase + (size_t)r * 2048 + col] = (f16)pacc[n][r];
    }
}

extern "C" void kernel_launch(void* const* d_in, const int* in_sizes, int n_in,
                              void* d_out, int out_size, void* d_ws, size_t ws_size,
                              hipStream_t stream) {
    (void)in_sizes; (void)n_in; (void)out_size; (void)ws_size;
    const float* hs   = (const float*)d_in[0];
    const float* cosb = (const float*)d_in[1];
    const float* sinb = (const float*)d_in[2];
    const float* qw   = (const float*)d_in[4];
    const float* kw   = (const float*)d_in[5];
    const float* vw   = (const float*)d_in[6];
    const float* ow   = (const float*)d_in[7];
    const float* qnw  = (const float*)d_in[8];
    const float* knw  = (const float*)d_in[9];

    float* out = (float*)d_out;
    float* probs = out + (size_t)2 * 2048 * 2560;          // output 1

    char* ws = (char*)d_ws;
    f16* hsb  = (f16*)(ws);                                // 20,971,520 B
    f16* wqkv = (f16*)(ws + 20971520);                     // 20,971,520 B
    f16* owb  = (f16*)(ws + 41943040);                     // 10,485,760 B
    f16* qkvh = (f16*)(ws + 52428800);                     // 33,554,432 B
    f16* qr   = (f16*)(ws + 85983232);                     // 16,777,216 B
    f16* kr   = (f16*)(ws + 102760448);                    //  8,388,608 B
    f16* vt   = (f16*)(ws + 111149056);                    //  8,388,608 B
    f16* attn = (f16*)(ws + 119537664);                    // 16,777,216 B

    // all fp32 -> fp16 casts in one launch
    cvt_all<<<12800, 256, 0, stream>>>(hs, qw, kw, vw, ow, hsb, wqkv, owb);

    // fused QKV projection: 256^2 BK=64 single-barrier pipeline, f16 out
    gemm256<2560, 4096, 16, true><<<256, 512, 0, stream>>>(hsb, wqkv, qkvh);

    // merged RMSNorm+RoPE + V transpose (one launch)
    rmsvt_k<<<12544, 256, 0, stream>>>(qkvh, cosb, sinb, qnw, knw, qr, kr, vt);

    // fused scores+softmax+probs+PV (dbuf K/V, counted vmcnt, NT probs stores)
    attn_fused<<<dim3(32, 16), 256, 0, stream>>>(qr, kr, vt, probs, attn);

    // O projection: 256^2 BK=64 single-barrier pipeline, NT f32 out (output 0)
    gemm256<2048, 2560, 10, false><<<160, 512, 0, stream>>>(attn, owb, out);
}